// Round 1
// 174.502 us; speedup vs baseline: 1.0291x; 1.0291x over previous
//
#include <hip/hip_runtime.h>
#include <math.h>

constexpr int B_ = 128;
constexpr int N_ = 512;
constexpr int K_ = 510;     // number of diagonals = N-2
constexpr int SPLIT = 16;   // compile-time: lets finalize's s-loop fully unroll

// Single-use streaming input: no reuse anywhere, so don't pollute L2.
#define NTL(p) __builtin_nontemporal_load(p)

// Kernel 1 (v2: phase-split, branch-free streams): thread t owns TWO
// diagonals, k_a = t (length 511-t) and k_b = 511-t (length t), processed
// as two SEPARATE unconditional loops instead of one fused predicated loop.
// Rationale: the fused version's 4 per-lane-divergent `if (p < lb)` loads
// per iteration force exec-mask save/restore regions between loads and give
// the scheduler divergent blocks to thread waitcnts around. Phase-split
// keeps per-wave balance exact (wave w: max_la + max_lb = (511-64w) +
// (64w+63) = 574 rows for EVERY wave) while making every macro-iteration
// 8 clean independent loads -> full MLP, zero exec juggling.
__global__ __launch_bounds__(256) void diag_partial_kernel(
    const float* __restrict__ in, float* __restrict__ ws) {
  const int b = blockIdx.x / SPLIT;
  const int s = blockIdx.x % SPLIT;
  const int t = threadIdx.x;            // t in [0,256)
  const float* base = in + (size_t)b * N_ * N_;
  constexpr size_t step = (size_t)SPLIT * (N_ + 1);
  float* w = ws + (size_t)blockIdx.x * (2 * N_);  // blockIdx.x == b*SPLIT+s

  // ---- Phase A: diagonal k_a = t, rows p = s, s+16, ... while p < la.
  {
    const int la = (N_ - 1) - t;        // 256..511 across lanes
    const float* pa = base + (size_t)s * (N_ + 1) + 1 + t;
    float S0 = 0.f, S1 = 0.f, S2 = 0.f, S3 = 0.f;
    float Q0 = 0.f, Q1 = 0.f, Q2 = 0.f, Q3 = 0.f;
    int p = s;
    for (; p + 7 * SPLIT < la; p += 8 * SPLIT) {
      float a0 = NTL(pa + 0 * step);
      float a1 = NTL(pa + 1 * step);
      float a2 = NTL(pa + 2 * step);
      float a3 = NTL(pa + 3 * step);
      float a4 = NTL(pa + 4 * step);
      float a5 = NTL(pa + 5 * step);
      float a6 = NTL(pa + 6 * step);
      float a7 = NTL(pa + 7 * step);
      S0 += a0; Q0 = fmaf(a0, a0, Q0);
      S1 += a1; Q1 = fmaf(a1, a1, Q1);
      S2 += a2; Q2 = fmaf(a2, a2, Q2);
      S3 += a3; Q3 = fmaf(a3, a3, Q3);
      S0 += a4; Q0 = fmaf(a4, a4, Q0);
      S1 += a5; Q1 = fmaf(a5, a5, Q1);
      S2 += a6; Q2 = fmaf(a6, a6, Q2);
      S3 += a7; Q3 = fmaf(a7, a7, Q3);
      pa += 8 * step;
    }
    for (; p < la; p += SPLIT) {
      float a = NTL(pa);
      S0 += a; Q0 = fmaf(a, a, Q0);
      pa += step;
    }
    w[t]      = (S0 + S1) + (S2 + S3);
    w[t + N_] = (Q0 + Q1) + (Q2 + Q3);
  }

  // ---- Phase B: diagonal k_b = 511 - t, rows p = s, s+16, ... while p < lb.
  {
    const int lb = t;                   // 0..255 across lanes
    const float* pb = base + (size_t)s * (N_ + 1) + (N_ - t);
    float S0 = 0.f, S1 = 0.f, S2 = 0.f, S3 = 0.f;
    float Q0 = 0.f, Q1 = 0.f, Q2 = 0.f, Q3 = 0.f;
    int p = s;
    for (; p + 7 * SPLIT < lb; p += 8 * SPLIT) {
      float a0 = NTL(pb + 0 * step);
      float a1 = NTL(pb + 1 * step);
      float a2 = NTL(pb + 2 * step);
      float a3 = NTL(pb + 3 * step);
      float a4 = NTL(pb + 4 * step);
      float a5 = NTL(pb + 5 * step);
      float a6 = NTL(pb + 6 * step);
      float a7 = NTL(pb + 7 * step);
      S0 += a0; Q0 = fmaf(a0, a0, Q0);
      S1 += a1; Q1 = fmaf(a1, a1, Q1);
      S2 += a2; Q2 = fmaf(a2, a2, Q2);
      S3 += a3; Q3 = fmaf(a3, a3, Q3);
      S0 += a4; Q0 = fmaf(a4, a4, Q0);
      S1 += a5; Q1 = fmaf(a5, a5, Q1);
      S2 += a6; Q2 = fmaf(a6, a6, Q2);
      S3 += a7; Q3 = fmaf(a7, a7, Q3);
      pb += 8 * step;
    }
    for (; p < lb; p += SPLIT) {
      float a = NTL(pb);
      S0 += a; Q0 = fmaf(a, a, Q0);
      pb += step;
    }
    // thread t writes k=t and k=511-t (disjoint: [0,256) vs [256,512))
    w[(N_ - 1) - t]      = (S0 + S1) + (S2 + S3);
    w[(N_ - 1) - t + N_] = (Q0 + Q1) + (Q2 + Q3);
  }
}

// Kernel 2: combine partials (fully-unrolled constant-trip loop -> 32
// independent loads in flight; runtime-split version serialized them and
// was ~20us at 128 blocks), compute scaled = sqrt(var)*len/5 per k,
// reduce mean over k, write both tuple outputs.
__global__ __launch_bounds__(512) void finalize_kernel(
    const float* __restrict__ ws, float* __restrict__ out) {
  __shared__ float red[8];
  const int b = blockIdx.x;
  const int t = threadIdx.x;
  float Ssum = 0.0f, Qsum = 0.0f;
#pragma unroll
  for (int s = 0; s < SPLIT; ++s) {
    const float* w = ws + (size_t)(b * SPLIT + s) * (2 * N_);
    Ssum += w[t];
    Qsum += w[t + N_];
  }
  float scaled = 0.0f;
  if (t < K_) {
    float len = (float)(N_ - 1 - t);
    float mean = Ssum / len;
    float var = (Qsum - Ssum * mean) / (len - 1.0f);
    var = fmaxf(var, 0.0f);        // guard tiny negative from rounding
    scaled = sqrtf(var) * len * 0.2f;
  }
  // wave-64 reduction
  for (int off = 32; off > 0; off >>= 1)
    scaled += __shfl_down(scaled, off, 64);
  const int wid = t >> 6;
  if ((t & 63) == 0) red[wid] = scaled;
  __syncthreads();
  if (t == 0) {
    float tot = 0.0f;
    for (int i = 0; i < 8; ++i) tot += red[i];
    float loss = tot / (float)K_;
    out[b] = loss;        // output 0: loss
    out[B_ + b] = loss;   // output 1: stop_gradient(loss) == loss
  }
}

extern "C" void kernel_launch(void* const* d_in, const int* in_sizes, int n_in,
                              void* d_out, int out_size, void* d_ws, size_t ws_size,
                              hipStream_t stream) {
  const float* in = (const float*)d_in[0];
  float* out = (float*)d_out;
  float* ws = (float*)d_ws;
  // 2048 blocks of 256 threads -> 8 blocks/CU, 32 waves/CU. ws use: 8 MB.
  diag_partial_kernel<<<B_ * SPLIT, 256, 0, stream>>>(in, ws);
  finalize_kernel<<<B_, 512, 0, stream>>>(ws, out);
}